// Round 2
// baseline (56.004 us; speedup 1.0000x reference)
//
#include <hip/hip_runtime.h>
#include <math.h>

#define BB 64
#define LL 512
#define DD 768
#define HH 768
#define KK 128

// ws layout (floats): feat[64*768] | h[64*768]
#define FEAT_OFF 0
#define H_OFF    (BB * DD)

// ---------------------------------------------------------------------------
// Kernel A: stream-compaction scan + span-max gather -> feat (B, D)
// grid: (B, 3) ; block: 256. Each block handles 256 of the 768 columns.
// ---------------------------------------------------------------------------
__global__ __launch_bounds__(256) void halton_feat_kernel(
    const float* __restrict__ enc,        // (B, L, D)
    const int*   __restrict__ valid_mask, // (B, L)
    const int*   __restrict__ pos_span,   // (B, 2)
    float*       __restrict__ feat)       // (B, D)
{
    __shared__ int s_idx[40];
    __shared__ int s_count;

    const int b    = blockIdx.x;
    const int part = blockIdx.y;          // 0..2
    const int tid  = threadIdx.x;
    const int lo   = pos_span[b * 2 + 0];
    const int hi   = pos_span[b * 2 + 1]; // <= 39 by construction

    // wave 0: ballot scan of the valid_mask row -> compacted indices
    if (tid < 64) {
        int count = 0;
        #pragma unroll
        for (int c = 0; c < LL / 64; ++c) {
            int l = c * 64 + tid;
            int v = valid_mask[b * LL + l];
            unsigned long long m = __ballot(v == 1);
            if (v == 1) {
                int rank = count + __popcll(m & ((1ull << tid) - 1ull));
                if (rank < 40) s_idx[rank] = l;
            }
            count += __popcll(m);
        }
        if (tid == 0) s_count = count;
    }
    __syncthreads();
    const int count = s_count;

    const int d = part * 256 + tid;       // column
    float m = -INFINITY;
    const int pend = min(hi, count - 1);
    for (int p = lo; p <= pend; ++p) {
        m = fmaxf(m, enc[((long)b * LL + s_idx[p]) * DD + d]);
    }
    if (hi >= count) m = fmaxf(m, 0.0f);  // zero row(s) inside span
    feat[b * DD + d] = m;
}

// ---------------------------------------------------------------------------
// Kernel B: h = relu(feat @ W1 + b1)
// grid: (12 j-tiles of 64, 8 b-tiles of 8) ; block: 128 threads.
// thread: j = tid&63 (one column), half = tid>>6, 4 batches -> 4 acc chains.
// ---------------------------------------------------------------------------
__global__ __launch_bounds__(128) void halton_gemm1_kernel(
    const float* __restrict__ feat,  // (B, D)
    const float* __restrict__ W1,    // (D, H)
    const float* __restrict__ b1,    // (H)
    float*       __restrict__ h)     // (B, H)
{
    __shared__ float s_feat[8 * DD]; // 24 KB

    const int tid   = threadIdx.x;
    const int jbase = blockIdx.x * 64;
    const int bbase = blockIdx.y * 8;

    // stage 8-batch feat panel (contiguous, coalesced)
    for (int i = tid; i < 8 * DD; i += 128) {
        s_feat[i] = feat[bbase * DD + i];
    }
    __syncthreads();

    const int j    = jbase + (tid & 63);
    const int half = tid >> 6;            // uniform per wave
    const float* f0 = &s_feat[(half * 4 + 0) * DD];
    const float* f1 = &s_feat[(half * 4 + 1) * DD];
    const float* f2 = &s_feat[(half * 4 + 2) * DD];
    const float* f3 = &s_feat[(half * 4 + 3) * DD];

    float acc0 = b1[j], acc1 = acc0, acc2 = acc0, acc3 = acc0;
    #pragma unroll 8
    for (int k = 0; k < DD; ++k) {
        const float w = W1[k * HH + j];   // coalesced, L1-shared across waves
        acc0 += f0[k] * w;                // LDS broadcast reads
        acc1 += f1[k] * w;
        acc2 += f2[k] * w;
        acc3 += f3[k] * w;
    }
    const int brow = bbase + half * 4;
    h[(brow + 0) * HH + j] = fmaxf(acc0, 0.0f);
    h[(brow + 1) * HH + j] = fmaxf(acc1, 0.0f);
    h[(brow + 2) * HH + j] = fmaxf(acc2, 0.0f);
    h[(brow + 3) * HH + j] = fmaxf(acc3, 0.0f);
}

// ---------------------------------------------------------------------------
// Kernel C: logits = h @ W2 + b2
// grid: (2 col-tiles of 64, 16 b-tiles of 4) ; block: 128 threads.
// thread: col = tid&63, half = tid>>6, 2 batches -> 2 acc chains.
// ---------------------------------------------------------------------------
__global__ __launch_bounds__(128) void halton_gemm2_kernel(
    const float* __restrict__ h,     // (B, H)
    const float* __restrict__ W2,    // (H, K)
    const float* __restrict__ b2,    // (K)
    float*       __restrict__ out)   // (B, K)
{
    __shared__ float s_h[4 * HH];    // 12 KB

    const int tid   = threadIdx.x;
    const int cbase = blockIdx.x * 64;
    const int bbase = blockIdx.y * 4;

    for (int i = tid; i < 4 * HH; i += 128) {
        s_h[i] = h[bbase * HH + i];
    }
    __syncthreads();

    const int col  = cbase + (tid & 63);
    const int half = tid >> 6;            // uniform per wave
    const float* h0 = &s_h[(half * 2 + 0) * HH];
    const float* h1 = &s_h[(half * 2 + 1) * HH];

    float acc0 = b2[col], acc1 = acc0;
    #pragma unroll 8
    for (int j = 0; j < HH; ++j) {
        const float w = W2[j * KK + col]; // coalesced
        acc0 += h0[j] * w;
        acc1 += h1[j] * w;
    }
    const int brow = bbase + half * 2;
    out[(brow + 0) * KK + col] = acc0;
    out[(brow + 1) * KK + col] = acc1;
}

extern "C" void kernel_launch(void* const* d_in, const int* in_sizes, int n_in,
                              void* d_out, int out_size, void* d_ws, size_t ws_size,
                              hipStream_t stream) {
    const float* enc        = (const float*)d_in[0];
    const float* W1         = (const float*)d_in[1];
    const float* b1         = (const float*)d_in[2];
    const float* W2         = (const float*)d_in[3];
    const float* b2         = (const float*)d_in[4];
    const int*   valid_mask = (const int*)d_in[5];
    const int*   pos_span   = (const int*)d_in[6];
    // d_in[7] = mask_span: dead code (mask_feat unused by the reference output)
    float* out  = (float*)d_out;
    float* feat = (float*)d_ws + FEAT_OFF;
    float* h    = (float*)d_ws + H_OFF;

    halton_feat_kernel<<<dim3(BB, 3), 256, 0, stream>>>(enc, valid_mask, pos_span, feat);
    halton_gemm1_kernel<<<dim3(12, 8), 128, 0, stream>>>(feat, W1, b1, h);
    halton_gemm2_kernel<<<dim3(2, 16), 128, 0, stream>>>(h, W2, b2, out);
}

// Round 3
// 37.391 us; speedup vs baseline: 1.4978x; 1.4978x over previous
//
#include <hip/hip_runtime.h>
#include <math.h>

#define BB 64
#define LL 512
#define DD 768
#define HH 768
#define KK 128

// ws layout (floats): feat[64*768] | h[64*768]
#define FEAT_OFF 0
#define H_OFF    (BB * DD)

// ---------------------------------------------------------------------------
// Kernel A: stream-compaction scan + span-max gather -> feat (B, D)
// grid: (B, 3) ; block: 256. Each block handles 256 of the 768 columns.
// ---------------------------------------------------------------------------
__global__ __launch_bounds__(256) void halton_feat_kernel(
    const float* __restrict__ enc,        // (B, L, D)
    const int*   __restrict__ valid_mask, // (B, L)
    const int*   __restrict__ pos_span,   // (B, 2)
    float*       __restrict__ feat)       // (B, D)
{
    __shared__ int s_idx[40];
    __shared__ int s_count;

    const int b    = blockIdx.x;
    const int part = blockIdx.y;          // 0..2
    const int tid  = threadIdx.x;
    const int lo   = pos_span[b * 2 + 0];
    const int hi   = pos_span[b * 2 + 1]; // <= 39 by construction

    // wave 0: ballot scan of the valid_mask row -> compacted indices
    if (tid < 64) {
        int count = 0;
        #pragma unroll
        for (int c = 0; c < LL / 64; ++c) {
            int l = c * 64 + tid;
            int v = valid_mask[b * LL + l];
            unsigned long long m = __ballot(v == 1);
            if (v == 1) {
                int rank = count + __popcll(m & ((1ull << tid) - 1ull));
                if (rank < 40) s_idx[rank] = l;
            }
            count += __popcll(m);
        }
        if (tid == 0) s_count = count;
    }
    __syncthreads();
    const int count = s_count;

    const int d = part * 256 + tid;       // column
    float m = -INFINITY;
    const int pend = min(hi, count - 1);
    for (int p = lo; p <= pend; ++p) {
        m = fmaxf(m, enc[((long)b * LL + s_idx[p]) * DD + d]);
    }
    if (hi >= count) m = fmaxf(m, 0.0f);  // zero row(s) inside span
    feat[b * DD + d] = m;
}

// ---------------------------------------------------------------------------
// Kernel B: h = relu(feat @ W1 + b1)
// grid: (12 j-tiles of 64, 8 b-tiles of 8) = 96 blocks ; block: 512 (8 waves).
// thread: j = tid&63 (column), bl = tid>>6 (batch within tile).
// feat row via float4 LDS broadcast; 4 accumulators break the FMA chain.
// ---------------------------------------------------------------------------
__global__ __launch_bounds__(512) void halton_gemm1_kernel(
    const float* __restrict__ feat,  // (B, D)
    const float* __restrict__ W1,    // (D, H)
    const float* __restrict__ b1,    // (H)
    float*       __restrict__ h)     // (B, H)
{
    __shared__ float s_feat[8 * DD]; // 24 KB

    const int tid   = threadIdx.x;
    const int jbase = blockIdx.x * 64;
    const int bbase = blockIdx.y * 8;

    // stage 8-batch feat panel: 6144 floats = 1536 float4, coalesced
    {
        const float4* src = (const float4*)&feat[bbase * DD];
        float4*       dst = (float4*)s_feat;
        for (int i = tid; i < 8 * DD / 4; i += 512) dst[i] = src[i];
    }
    __syncthreads();

    const int j  = jbase + (tid & 63);
    const int bl = tid >> 6;              // 0..7, uniform per wave
    const float4* f4 = (const float4*)&s_feat[bl * DD];
    const float*  w  = &W1[j];

    float acc0 = b1[j], acc1 = 0.0f, acc2 = 0.0f, acc3 = 0.0f;
    #pragma unroll 4
    for (int k4 = 0; k4 < DD / 4; ++k4) {
        const float4 fv = f4[k4];         // LDS b128 broadcast (wave-uniform)
        const float* wk = &w[k4 * 4 * HH];
        acc0 += fv.x * wk[0 * HH];        // coalesced 256B/wave, L1-shared
        acc1 += fv.y * wk[1 * HH];
        acc2 += fv.z * wk[2 * HH];
        acc3 += fv.w * wk[3 * HH];
    }
    h[(bbase + bl) * HH + j] = fmaxf((acc0 + acc1) + (acc2 + acc3), 0.0f);
}

// ---------------------------------------------------------------------------
// Kernel C: logits = h @ W2 + b2
// grid: (1, 32 b-tiles of 2) = 32 blocks ; block: 256 (4 waves).
// thread: col = tid&127, bl = tid>>7 (batch within tile).
// ---------------------------------------------------------------------------
__global__ __launch_bounds__(256) void halton_gemm2_kernel(
    const float* __restrict__ h,     // (B, H)
    const float* __restrict__ W2,    // (H, K)
    const float* __restrict__ b2,    // (K)
    float*       __restrict__ out)   // (B, K)
{
    __shared__ float s_h[2 * HH];    // 6 KB

    const int tid   = threadIdx.x;
    const int bbase = blockIdx.y * 2;

    {
        const float4* src = (const float4*)&h[bbase * HH];
        float4*       dst = (float4*)s_h;
        for (int i = tid; i < 2 * HH / 4; i += 256) dst[i] = src[i];
    }
    __syncthreads();

    const int col = tid & 127;
    const int bl  = tid >> 7;             // 0..1, uniform per wave
    const float4* h4 = (const float4*)&s_h[bl * HH];
    const float*  w  = &W2[col];

    float acc0 = b2[col], acc1 = 0.0f, acc2 = 0.0f, acc3 = 0.0f;
    #pragma unroll 8
    for (int j4 = 0; j4 < HH / 4; ++j4) {
        const float4 hv = h4[j4];         // LDS b128 broadcast
        const float* wj = &w[j4 * 4 * KK];
        acc0 += hv.x * wj[0 * KK];        // coalesced
        acc1 += hv.y * wj[1 * KK];
        acc2 += hv.z * wj[2 * KK];
        acc3 += hv.w * wj[3 * KK];
    }
    out[(bbase + bl) * KK + col] = (acc0 + acc1) + (acc2 + acc3);
}

extern "C" void kernel_launch(void* const* d_in, const int* in_sizes, int n_in,
                              void* d_out, int out_size, void* d_ws, size_t ws_size,
                              hipStream_t stream) {
    const float* enc        = (const float*)d_in[0];
    const float* W1         = (const float*)d_in[1];
    const float* b1         = (const float*)d_in[2];
    const float* W2         = (const float*)d_in[3];
    const float* b2         = (const float*)d_in[4];
    const int*   valid_mask = (const int*)d_in[5];
    const int*   pos_span   = (const int*)d_in[6];
    // d_in[7] = mask_span: dead code (mask_feat unused by the reference output)
    float* out  = (float*)d_out;
    float* feat = (float*)d_ws + FEAT_OFF;
    float* h    = (float*)d_ws + H_OFF;

    halton_feat_kernel<<<dim3(BB, 3), 256, 0, stream>>>(enc, valid_mask, pos_span, feat);
    halton_gemm1_kernel<<<dim3(12, 8), 512, 0, stream>>>(feat, W1, b1, h);
    halton_gemm2_kernel<<<dim3(1, 32), 256, 0, stream>>>(h, W2, b2, out);
}